// Round 1
// 709.605 us; speedup vs baseline: 1.0578x; 1.0578x over previous
//
#include <hip/hip_runtime.h>

#define NT 320          // threads/block (5 waves)
#define TZ 4
#define TH 4
#define PZ 6            // TZ+2
#define PH 6            // TH+2
#define STR 84          // LDS row stride in floats: 20 data slots + 1 pad slot (odd slot stride de-phases rows)
#define PROWS (PZ*PH)   // 36 rows per channel tile
#define NSLOT (PROWS*20)// 720 float4 staging slots per channel

__device__ __forceinline__ void store_f4u(float* p, float4 v) {
    __builtin_memcpy(p, &v, 16);   // unaligned-safe 16B store
}

__global__ __launch_bounds__(NT)
void wincorr_kernel(const float* __restrict__ x, const float* __restrict__ y,
                    float* __restrict__ out)
{
    __shared__ __align__(16) float buf[2][PROWS * STR];

    const long long plane = 512000;  // 80*80*80
    const int tid = threadIdx.x;
    const int twi = tid % 20;        // float4 column within row (w = 4*twi)
    const int th  = (tid / 20) % TH;
    const int tz  = tid / 80;

    const int zt = blockIdx.x, ht = blockIdx.y, b = blockIdx.z;
    const int z0 = zt * TZ, h0 = ht * TH;
    const int gz = z0 + tz, gh = h0 + th, wb = 4 * twi;

    const float* xb = x + (long long)b * 64 * plane;
    const float* yb = y + (long long)b * 64 * plane;
    const long long xoff = (long long)gz * 6400 + gh * 80 + wb;
    // clamped offsets for the two edge scalars of x (loaded value unused at true w-edges)
    const long long xoffm = xoff - (wb > 0 ? 1 : 0);   // x[wb-1]
    const long long xoffp = xoff + (wb < 76 ? 4 : 3);  // x[wb+4]

    // ---- staging precompute: 3 float4 slots per thread (720 slots total) ----
    int  goff[3], loff[3];
    bool val[3];
    const bool inr2 = (tid + 2 * NT) < NSLOT;   // k=0,1 always in range
#pragma unroll
    for (int k = 0; k < 3; ++k) {
        int s   = tid + k * NT;
        int row = s / 20, col = s % 20;
        int pz = row / PH, py = row % PH;
        int yz = z0 - 1 + pz, yh = h0 - 1 + py;
        bool ok = (s < NSLOT) && ((unsigned)yz < 80u) && ((unsigned)yh < 80u);
        val[k]  = ok;
        goff[k] = yz * 6400 + yh * 80 + 4 * col;
        loff[k] = row * STR + 4 * col;
    }

    float4 acc[27];
#pragma unroll
    for (int o = 0; o < 27; ++o) acc[o] = make_float4(0.f, 0.f, 0.f, 0.f);

    const float4 zero4 = make_float4(0.f, 0.f, 0.f, 0.f);
    float4 v0, v1, v2;

    // preload channel 0
    {
        const float* yc = yb;
        v0 = val[0] ? *(const float4*)(yc + goff[0]) : zero4;
        v1 = val[1] ? *(const float4*)(yc + goff[1]) : zero4;
        v2 = val[2] ? *(const float4*)(yc + goff[2]) : zero4;
        *(float4*)(&buf[0][loff[0]]) = v0;
        *(float4*)(&buf[0][loff[1]]) = v1;
        if (inr2) *(float4*)(&buf[0][loff[2]]) = v2;
    }
    __syncthreads();

    for (int c = 0; c < 64; ++c) {
        const float* xcp = xb + (long long)c * plane;
        const float4 xv  = *(const float4*)(xcp + xoff);
        const float  xml = xcp[xoffm];   // x[wb-1]  (don't-care at twi==0)
        const float  xpr = xcp[xoffp];   // x[wb+4]  (don't-care at twi==19)

        // issue next channel's global loads (latency overlapped with compute)
        if (c < 63) {
            const float* yc = yb + (long long)(c + 1) * plane;
            v0 = val[0] ? *(const float4*)(yc + goff[0]) : zero4;
            v1 = val[1] ? *(const float4*)(yc + goff[1]) : zero4;
            v2 = val[2] ? *(const float4*)(yc + goff[2]) : zero4;
        }

        const float* B = buf[c & 1];
#pragma unroll
        for (int dz = 0; dz < 3; ++dz) {
#pragma unroll
            for (int dy = 0; dy < 3; ++dy) {
                // single aligned b128 per tap-row: y[row][wb..wb+3]
                const float4 r = *(const float4*)(B + ((tz + dz) * PH + (th + dy)) * STR + wb);
                const int o = (dz * 3 + dy) * 3;
                // t=0 (dx=-1): outputs [wb+1..wb+4] = x[wb+1..wb+4] * y[wb..wb+3]
                acc[o].x   += xv.y * r.x; acc[o].y   += xv.z * r.y;
                acc[o].z   += xv.w * r.z; acc[o].w   += xpr  * r.w;
                // t=1 (dx= 0): outputs [wb..wb+3]
                acc[o+1].x += xv.x * r.x; acc[o+1].y += xv.y * r.y;
                acc[o+1].z += xv.z * r.z; acc[o+1].w += xv.w * r.w;
                // t=2 (dx=+1): outputs [wb-1..wb+2] = x[wb-1..wb+2] * y[wb..wb+3]
                acc[o+2].x += xml  * r.x; acc[o+2].y += xv.x * r.y;
                acc[o+2].z += xv.y * r.z; acc[o+2].w += xv.z * r.w;
            }
        }

        if (c < 63) {
            float* W = (float*)buf[(c + 1) & 1];
            *(float4*)(W + loff[0]) = v0;
            *(float4*)(W + loff[1]) = v1;
            if (inr2) *(float4*)(W + loff[2]) = v2;
        }
        __syncthreads();
    }

    // epilogue: scale by 64^-0.5 = 0.125; shifted windows per dx tap
    float* ob = out + (long long)b * 27 * plane + xoff;
#pragma unroll
    for (int dz = 0; dz < 3; ++dz) {
#pragma unroll
        for (int dy = 0; dy < 3; ++dy) {
            const int o = (dz * 3 + dy) * 3;
            float4 a0 = acc[o], a1 = acc[o+1], a2 = acc[o+2];
            a0.x *= 0.125f; a0.y *= 0.125f; a0.z *= 0.125f; a0.w *= 0.125f;
            a1.x *= 0.125f; a1.y *= 0.125f; a1.z *= 0.125f; a1.w *= 0.125f;
            a2.x *= 0.125f; a2.y *= 0.125f; a2.z *= 0.125f; a2.w *= 0.125f;
            float* p0 = ob + (long long)(o    ) * plane;
            float* p1 = ob + (long long)(o + 1) * plane;
            float* p2 = ob + (long long)(o + 2) * plane;
            // t=0 (dx=-1): window [wb+1..wb+4]
            if (twi < 19) store_f4u(p0 + 1, a0);
            else { p0[1] = a0.x; p0[2] = a0.y; p0[3] = a0.z; }  // w=77,78,79; drop w=80
            if (twi == 0) p0[0] = 0.f;                          // out[w=0] = x[0]*y[-1] = 0
            // t=1 (dx=0): aligned at wb
            *(float4*)p1 = a1;
            // t=2 (dx=+1): window [wb-1..wb+2]
            if (twi > 0) store_f4u(p2 - 1, a2);
            else { p2[0] = a2.y; p2[1] = a2.z; p2[2] = a2.w; }  // w=0,1,2; drop w=-1
            if (twi == 19) p2[3] = 0.f;                         // out[w=79] = x[79]*y[80] = 0
        }
    }
}

extern "C" void kernel_launch(void* const* d_in, const int* in_sizes, int n_in,
                              void* d_out, int out_size, void* d_ws, size_t ws_size,
                              hipStream_t stream) {
    const float* x = (const float*)d_in[0];
    const float* y = (const float*)d_in[1];
    float* out = (float*)d_out;

    dim3 grid(80 / TZ, 80 / TH, 2);   // (20, 20, 2) = 800 blocks
    dim3 block(NT);
    wincorr_kernel<<<grid, block, 0, stream>>>(x, y, out);
}